// Round 9
// baseline (188.678 us; speedup 1.0000x reference)
//
#include <hip/hip_runtime.h>
#include <cstdint>
#include <cmath>

#define B_ 2
#define C_ 64
#define H_ 128
#define W_ 240
#define HW_ (H_*W_)
#define OFF_CH 144
#define MASK_CH 72
#define ALIGNED_SZ (B_*C_*HW_)   /* 3932160 floats */

typedef __bf16 bf16x8 __attribute__((ext_vector_type(8)));
typedef float f32x4 __attribute__((ext_vector_type(4)));
typedef short short4v __attribute__((ext_vector_type(4)));
typedef unsigned short ushort_t;

__device__ __forceinline__ ushort_t f2bf(float f) {
    unsigned u = __float_as_uint(f);
    u += 0x7fffu + ((u >> 16) & 1u);          // round-to-nearest-even
    return (ushort_t)(u >> 16);
}
__device__ __forceinline__ float bf2f(ushort_t b) {
    return __uint_as_float((unsigned)b << 16);
}
__device__ __forceinline__ float bf_lo(int q) {
    return __uint_as_float((unsigned)q << 16);
}
__device__ __forceinline__ float bf_hi(int q) {
    return __uint_as_float((unsigned)q & 0xffff0000u);
}

// workspace layout (byte offsets); total 32,956,416 B (< 33.4 MB proven OK)
#define W1P_OFF  0u
#define W2P_OFF  147456u
#define PIN_OFF  442368u      /* [B][2][HW][64] bf16 = 15,728,640 */
#define HBUF_OFF 16171008u    /* [B][H][W][64]  bf16 =  7,864,320 */
#define MASK_OFF 24035328u    /* [B][72][H][W]  bf16 =  8,847,360 */
#define WDP_OFF  32882688u    /* [18][4][64][8] bf16 =     73,728 */

// ---------------------------------------------------------------------------
// Repack all weights into MFMA A-fragment layouts (unchanged, proven).
// ---------------------------------------------------------------------------
__global__ __launch_bounds__(256) void pack_weights(
    const float* __restrict__ w1, const float* __restrict__ w2,
    const float* __restrict__ wd,
    ushort_t* __restrict__ w1pf, ushort_t* __restrict__ w2pf,
    ushort_t* __restrict__ wdp)
{
    int t = blockIdx.x * 256 + threadIdx.x;
    if (t < 73728) {
        int j = t & 7, lane = (t >> 3) & 63, r = t >> 9;
        int wv = r & 3, ct = r >> 2;
        int tap = ct % 9, chunk = ct / 9;
        int oc = wv * 16 + (lane & 15);
        int ci = chunk * 32 + ((lane >> 4) << 3) + j;
        w1pf[t] = f2bf(w1[((size_t)oc * 128 + ci) * 9 + tap]);
    } else if (t < 73728 + 147456) {
        int f = t - 73728;
        int j = f & 7, lane = (f >> 3) & 63, r = f >> 9;
        int wv = r & 3, q = r >> 2;
        int tap = q % 9, oc2 = q / 9;
        int chunk = oc2 & 1, ocg = oc2 >> 1;
        int oc = ocg * 64 + wv * 16 + (lane & 15);
        int ci = chunk * 32 + ((lane >> 4) << 3) + j;
        float v = (oc < 216) ? w2[((size_t)oc * 64 + ci) * 9 + tap] : 0.f;
        w2pf[f] = f2bf(v);
    } else if (t < 73728 + 147456 + 36864) {
        int f = t - 221184;
        int j = f & 7, lane = (f >> 3) & 63, sg = f >> 9;
        int g = sg & 3, s = sg >> 2;
        int oc = g * 16 + (lane & 15);
        int K = s * 32 + ((lane >> 4) << 3) + j;
        int dg = K / 72, rr = K - dg * 72;
        int tap = rr >> 3, ci = (dg << 3) + (rr & 7);
        wdp[f] = f2bf(wd[((size_t)oc * 64 + ci) * 9 + tap]);
    }
}

// ---------------------------------------------------------------------------
// Repack input into SPLIT layout (unchanged).
// ---------------------------------------------------------------------------
__global__ __launch_bounds__(256) void pack_input(
    const float* __restrict__ nbr, const float* __restrict__ ref,
    ushort_t* __restrict__ pin)
{
    int f = blockIdx.x * 256 + threadIdx.x;    // < 983040 = B*HW*16
    int civec = f & 15;
    int rem = f >> 4;                          // b*HW + pix
    int b = rem / HW_, pix = rem - b * HW_;
    const int half = civec >> 3;
    const float* src = (half == 0) ? (nbr + (size_t)b * 64 * HW_)
                                   : (ref + (size_t)b * 64 * HW_);
    int cbase = (civec & 7) * 8;
    union { ushort_t u[8]; int4 v; } o;
#pragma unroll
    for (int j = 0; j < 8; ++j)
        o.u[j] = f2bf(src[(size_t)(cbase + j) * HW_ + pix]);
    *(int4*)&pin[(((size_t)b * 2 + half) * HW_ + pix) * 64 + cbase] = o.v;
}

// ---------------------------------------------------------------------------
// conv1 via MFMA implicit GEMM (unchanged, proven).
// ---------------------------------------------------------------------------
__global__ __launch_bounds__(256) void conv1_mfma(
    const ushort_t* __restrict__ pin, const float* __restrict__ b1,
    const ushort_t* __restrict__ w1pf, ushort_t* __restrict__ hbuf)
{
    const int bx = blockIdx.x, y = blockIdx.y, b = blockIdx.z;
    const int x0 = bx * 48;
    const int tid = threadIdx.x;
    const int wv = tid >> 6, lane = tid & 63;
    const int l15 = lane & 15, k8 = (lane >> 4) << 3;

    __shared__ __align__(16) ushort_t s_in[3 * 50 * 40];

    f32x4 acc[3];
#pragma unroll
    for (int i = 0; i < 3; ++i) acc[i] = (f32x4){0.f, 0.f, 0.f, 0.f};

    for (int chunk = 0; chunk < 4; ++chunk) {
        const int ci0 = chunk << 5;
        for (int i = tid; i < 600; i += 256) {
            int cvec = i & 3, rc = i >> 2;
            int row = rc / 50, col = rc - row * 50;
            int gy = y + row - 1, gx = x0 + col - 1;
            int ci = ci0 + cvec * 8;
            int half = ci >> 6, cw = ci & 63;
            int4 v = {0, 0, 0, 0};
            if ((unsigned)gy < (unsigned)H_ && (unsigned)gx < (unsigned)W_)
                v = *(const int4*)&pin[(((size_t)b * 2 + half) * HW_ + (size_t)gy * W_ + gx) * 64 + cw];
            *(int4*)&s_in[(row * 50 + col) * 40 + cvec * 8] = v;
        }
        bf16x8 af[9];
#pragma unroll
        for (int tap = 0; tap < 9; ++tap)
            af[tap] = *(const bf16x8*)&w1pf[((((size_t)chunk * 9 + tap) * 4 + wv) * 64 + lane) * 8];
        __syncthreads();

#pragma unroll
        for (int tap = 0; tap < 9; ++tap) {
            const int ky = tap / 3, kx = tap - ky * 3;
#pragma unroll
            for (int pt = 0; pt < 3; ++pt) {
                int col = (pt << 4) + l15 + kx;
                bf16x8 bb = *(const bf16x8*)&s_in[(ky * 50 + col) * 40 + k8];
                acc[pt] = __builtin_amdgcn_mfma_f32_16x16x32_bf16(af[tap], bb, acc[pt], 0, 0, 0);
            }
        }
        __syncthreads();
    }

    const int ocb = (wv << 4) + ((lane >> 4) << 2);
    float bias[4];
#pragma unroll
    for (int r = 0; r < 4; ++r) bias[r] = b1[ocb + r];
#pragma unroll
    for (int pt = 0; pt < 3; ++pt) {
        int gx = x0 + (pt << 4) + l15;
        union { ushort_t u[4]; short4v s; } o;
#pragma unroll
        for (int r = 0; r < 4; ++r) {
            float v = acc[pt][r] + bias[r];
            v = (v >= 0.f) ? v : 0.1f * v;
            o.u[r] = f2bf(v);
        }
        *(short4v*)&hbuf[(((size_t)b * H_ + y) * W_ + gx) * 64 + ocb] = o.s;
    }
}

// ---------------------------------------------------------------------------
// conv2 via MFMA implicit GEMM (unchanged, proven).
// ---------------------------------------------------------------------------
__global__ __launch_bounds__(256) void conv2_mfma(
    const ushort_t* __restrict__ hbuf, const float* __restrict__ b2,
    const ushort_t* __restrict__ w2pf,
    float* __restrict__ off_out, ushort_t* __restrict__ maskbuf)
{
    const int bx = blockIdx.x, y = blockIdx.y;
    const int b = blockIdx.z >> 2, ocg = blockIdx.z & 3;
    const int x0 = bx * 48;
    const int tid = threadIdx.x;
    const int wv = tid >> 6, lane = tid & 63;
    const int l15 = lane & 15, k8 = (lane >> 4) << 3;

    __shared__ __align__(16) ushort_t s_in[3 * 50 * 40];

    f32x4 acc[3];
#pragma unroll
    for (int i = 0; i < 3; ++i) acc[i] = (f32x4){0.f, 0.f, 0.f, 0.f};

    for (int chunk = 0; chunk < 2; ++chunk) {
        const int ci0 = chunk << 5;
        for (int i = tid; i < 600; i += 256) {
            int cvec = i & 3, rc = i >> 2;
            int row = rc / 50, col = rc - row * 50;
            int gy = y + row - 1, gx = x0 + col - 1;
            int4 v = {0, 0, 0, 0};
            if ((unsigned)gy < (unsigned)H_ && (unsigned)gx < (unsigned)W_)
                v = *(const int4*)&hbuf[(((size_t)b * H_ + gy) * W_ + gx) * 64 + ci0 + cvec * 8];
            *(int4*)&s_in[(row * 50 + col) * 40 + cvec * 8] = v;
        }
        bf16x8 af[9];
#pragma unroll
        for (int tap = 0; tap < 9; ++tap)
            af[tap] = *(const bf16x8*)&w2pf[(((((size_t)ocg * 2 + chunk) * 9 + tap) * 4 + wv) * 64 + lane) * 8];
        __syncthreads();

#pragma unroll
        for (int tap = 0; tap < 9; ++tap) {
            const int ky = tap / 3, kx = tap - ky * 3;
#pragma unroll
            for (int pt = 0; pt < 3; ++pt) {
                int col = (pt << 4) + l15 + kx;
                bf16x8 bb = *(const bf16x8*)&s_in[(ky * 50 + col) * 40 + k8];
                acc[pt] = __builtin_amdgcn_mfma_f32_16x16x32_bf16(af[tap], bb, acc[pt], 0, 0, 0);
            }
        }
        __syncthreads();
    }

    const int ocb = (wv << 4) + ((lane >> 4) << 2);
#pragma unroll
    for (int pt = 0; pt < 3; ++pt) {
        int gx = x0 + (pt << 4) + l15;
#pragma unroll
        for (int r = 0; r < 4; ++r) {
            int co = (ocg << 6) + ocb + r;
            if (co < 216) {
                float v = acc[pt][r] + b2[co];
                if (co < 144) {
                    off_out[((size_t)b * OFF_CH + co) * HW_ + y * W_ + gx] = v;
                } else {
                    maskbuf[((size_t)b * MASK_CH + (co - 144)) * HW_ + y * W_ + gx] =
                        f2bf(1.f / (1.f + expf(-v)));
                }
            }
        }
    }
}

// ---------------------------------------------------------------------------
// dconv v6: barrier-free + 3-DEEP gather pipeline.
// Wave = 16 px (one row) x 64 oc x full K; lane (l15,hi4) owns
// (px=x0+l15, kgroup=hi4). Gathers issued 3 slices ahead, offsets 4 ahead;
// blend of stage A placed BEFORE the stage-D issue so registers retire.
// ---------------------------------------------------------------------------
__global__ __launch_bounds__(256, 4) void dconv_mfma(
    const ushort_t* __restrict__ pin,
    const float* __restrict__ offs,
    const ushort_t* __restrict__ maskbuf,
    const ushort_t* __restrict__ wdp, const float* __restrict__ bd,
    float* __restrict__ outp)
{
    const int bid = blockIdx.x;
    const int nid = (bid & 7) * 120 + (bid >> 3);
    const int b   = nid / 480;
    const int rr_ = nid - b * 480;
    const int byt = rr_ / 15, bxt = rr_ - byt * 15;   // byt 0..31
    const int x0 = bxt << 4, y0 = byt << 2;

    const int tid = threadIdx.x;
    const int wv = tid >> 6, lane = tid & 63;
    const int l15 = lane & 15, hi4 = lane >> 4;       // hi4 = k-group

    const int x = x0 + l15, y = y0 + wv;              // this lane's pixel
    const size_t pix = (size_t)y * W_ + x;
    const size_t pinb = (size_t)(b * 2) * HW_;        // nbr half base
    const float* offp = offs + (size_t)b * OFF_CH * HW_ + pix;
    const ushort_t* mkp = maskbuf + (size_t)b * MASK_CH * HW_ + pix;

    f32x4 acc0 = {0.f,0.f,0.f,0.f}, acc1 = {0.f,0.f,0.f,0.f};
    f32x4 acc2 = {0.f,0.f,0.f,0.f}, acc3 = {0.f,0.f,0.f,0.f};

    auto load_off = [&](int s, float& dy, float& dx, float& m) {
        int K = (s << 5) + (hi4 << 3);
        int dg = K / 72, r2 = K - dg * 72, tap = r2 >> 3;
        dy = offp[(size_t)(dg * 18 + tap) * HW_];
        dx = offp[(size_t)(dg * 18 + 9 + tap) * HW_];
        m  = bf2f(mkp[(size_t)(dg * 9 + tap) * HW_]);
    };
    auto sample = [&](int s, float dyv, float dxv, float m,
                      float& r0, float& r1, float& r2, float& r3,
                      int4& g0, int4& g1, int4& g2, int4& g3) {
        int K = (s << 5) + (hi4 << 3);
        int dg = K / 72, rm = K - dg * 72, tap = rm >> 3;
        int ky = tap / 3 - 1, kx = tap % 3 - 1;
        float py  = (float)(y + ky) + dyv;
        float pxf = (float)(x + kx) + dxv;
        float yf = floorf(py), xf = floorf(pxf);
        float wy = py - yf, wx = pxf - xf;
        int yi = (int)yf, xi = (int)xf;
        bool y0v = (unsigned)yi < (unsigned)H_;
        bool y1v = (unsigned)(yi + 1) < (unsigned)H_;
        bool x0v = (unsigned)xi < (unsigned)W_;
        bool x1v = (unsigned)(xi + 1) < (unsigned)W_;
        r0 = (1.f - wy) * (1.f - wx) * m; if (!(y0v && x0v)) r0 = 0.f;
        r1 = (1.f - wy) * wx         * m; if (!(y0v && x1v)) r1 = 0.f;
        r2 = wy         * (1.f - wx) * m; if (!(y1v && x0v)) r2 = 0.f;
        r3 = wy         * wx         * m; if (!(y1v && x1v)) r3 = 0.f;
        int yc0 = min(max(yi, 0), H_ - 1), yc1 = min(max(yi + 1, 0), H_ - 1);
        int xc0 = min(max(xi, 0), W_ - 1), xc1 = min(max(xi + 1, 0), W_ - 1);
        const int cofs = dg << 3;
        g0 = *(const int4*)&pin[(pinb + yc0 * W_ + xc0) * 64 + cofs];
        g1 = *(const int4*)&pin[(pinb + yc0 * W_ + xc1) * 64 + cofs];
        g2 = *(const int4*)&pin[(pinb + yc1 * W_ + xc0) * 64 + cofs];
        g3 = *(const int4*)&pin[(pinb + yc1 * W_ + xc1) * 64 + cofs];
    };

    // ---- prologue: fill 3 gather stages, offsets one slice further ----
    float tdy, tdx, tm;
    float wA0, wA1, wA2, wA3;  int4 qA0, qA1, qA2, qA3;
    float wB0, wB1, wB2, wB3;  int4 qB0, qB1, qB2, qB3;
    float wC0, wC1, wC2, wC3;  int4 qC0, qC1, qC2, qC3;
    float dyD, dxD, mD;

    load_off(0, tdy, tdx, tm);
    sample(0, tdy, tdx, tm, wA0, wA1, wA2, wA3, qA0, qA1, qA2, qA3);
    load_off(1, tdy, tdx, tm);
    sample(1, tdy, tdx, tm, wB0, wB1, wB2, wB3, qB0, qB1, qB2, qB3);
    load_off(2, tdy, tdx, tm);
    sample(2, tdy, tdx, tm, wC0, wC1, wC2, wC3, qC0, qC1, qC2, qC3);
    load_off(3, dyD, dxD, mD);

#pragma unroll 3
    for (int s = 0; s < 18; ++s) {
        // A-fragments for slice s (L1/L2-resident)
        const ushort_t* wp = wdp + (((size_t)(s << 2) * 64) + lane) * 8;
        bf16x8 a0 = *(const bf16x8*)(wp);
        bf16x8 a1 = *(const bf16x8*)(wp + 512);
        bf16x8 a2 = *(const bf16x8*)(wp + 1024);
        bf16x8 a3 = *(const bf16x8*)(wp + 1536);

        // blend stage A (gathers issued 3 slices ago) -> frees qA regs
        bf16x8 bfrag;
        {
            const int* c00 = (const int*)&qA0; const int* c01 = (const int*)&qA1;
            const int* c10 = (const int*)&qA2; const int* c11 = (const int*)&qA3;
#pragma unroll
            for (int j = 0; j < 4; ++j) {
                float lo = wA0 * bf_lo(c00[j]) + wA1 * bf_lo(c01[j])
                         + wA2 * bf_lo(c10[j]) + wA3 * bf_lo(c11[j]);
                float hv = wA0 * bf_hi(c00[j]) + wA1 * bf_hi(c01[j])
                         + wA2 * bf_hi(c10[j]) + wA3 * bf_hi(c11[j]);
                bfrag[2 * j]     = (__bf16)lo;
                bfrag[2 * j + 1] = (__bf16)hv;
            }
        }

        // issue gathers for s+3 into stage D (reuses stage-A registers)
        float wD0 = 0.f, wD1 = 0.f, wD2 = 0.f, wD3 = 0.f;
        int4 qD0 = {0,0,0,0}, qD1 = {0,0,0,0}, qD2 = {0,0,0,0}, qD3 = {0,0,0,0};
        if (s + 3 < 18)
            sample(s + 3, dyD, dxD, mD, wD0, wD1, wD2, wD3, qD0, qD1, qD2, qD3);

        // offsets for s+4
        if (s + 4 < 18) load_off(s + 4, dyD, dxD, mD);

        acc0 = __builtin_amdgcn_mfma_f32_16x16x32_bf16(a0, bfrag, acc0, 0, 0, 0);
        acc1 = __builtin_amdgcn_mfma_f32_16x16x32_bf16(a1, bfrag, acc1, 0, 0, 0);
        acc2 = __builtin_amdgcn_mfma_f32_16x16x32_bf16(a2, bfrag, acc2, 0, 0, 0);
        acc3 = __builtin_amdgcn_mfma_f32_16x16x32_bf16(a3, bfrag, acc3, 0, 0, 0);

        // rotate stages (unroll-3 renames these away)
        wA0 = wB0; wA1 = wB1; wA2 = wB2; wA3 = wB3;
        qA0 = qB0; qA1 = qB1; qA2 = qB2; qA3 = qB3;
        wB0 = wC0; wB1 = wC1; wB2 = wC2; wB3 = wC3;
        qB0 = qC0; qB1 = qC1; qB2 = qC2; qB3 = qC3;
        wC0 = wD0; wC1 = wD1; wC2 = wD2; wC3 = wD3;
        qC0 = qD0; qC1 = qD1; qC2 = qD2; qC3 = qD3;
    }

    // epilogue: acc_g[r] -> oc = g*16 + hi4*4 + r at pixel (y, x0+l15)
    const int ocr = hi4 << 2;
    const size_t pbase = (size_t)b * C_ * HW_ + (size_t)y * W_ + x0 + l15;
#pragma unroll
    for (int r = 0; r < 4; ++r) {
        int oc0 = ocr + r;
        outp[pbase + (size_t)(oc0)      * HW_] = acc0[r] + bd[oc0];
        outp[pbase + (size_t)(oc0 + 16) * HW_] = acc1[r] + bd[oc0 + 16];
        outp[pbase + (size_t)(oc0 + 32) * HW_] = acc2[r] + bd[oc0 + 32];
        outp[pbase + (size_t)(oc0 + 48) * HW_] = acc3[r] + bd[oc0 + 48];
    }
}

// ---------------------------------------------------------------------------
extern "C" void kernel_launch(void* const* d_in, const int* in_sizes, int n_in,
                              void* d_out, int out_size, void* d_ws, size_t ws_size,
                              hipStream_t stream)
{
    const float* nbr = (const float*)d_in[0];
    const float* ref = (const float*)d_in[1];
    const float* w1  = (const float*)d_in[2];
    const float* b1  = (const float*)d_in[3];
    const float* w2  = (const float*)d_in[4];
    const float* b2  = (const float*)d_in[5];
    const float* wd  = (const float*)d_in[6];
    const float* bd  = (const float*)d_in[7];

    float* out     = (float*)d_out;
    float* off_out = out + ALIGNED_SZ;

    char* ws = (char*)d_ws;
    ushort_t* w1pf  = (ushort_t*)(ws + W1P_OFF);
    ushort_t* w2pf  = (ushort_t*)(ws + W2P_OFF);
    ushort_t* pin   = (ushort_t*)(ws + PIN_OFF);
    ushort_t* hbufp = (ushort_t*)(ws + HBUF_OFF);
    ushort_t* maskp = (ushort_t*)(ws + MASK_OFF);
    ushort_t* wdp   = (ushort_t*)(ws + WDP_OFF);

    dim3 blk(256, 1, 1);
    pack_weights<<<1008, blk, 0, stream>>>(w1, w2, wd, w1pf, w2pf, wdp);
    pack_input<<<3840, blk, 0, stream>>>(nbr, ref, pin);
    conv1_mfma<<<dim3(5, 128, 2), blk, 0, stream>>>(pin, b1, w1pf, hbufp);
    conv2_mfma<<<dim3(5, 128, 8), blk, 0, stream>>>(hbufp, b2, w2pf, off_out, maskp);
    dconv_mfma<<<960, blk, 0, stream>>>(pin, off_out, maskp, wdp, bd, out);
}

// Round 10
// 159.589 us; speedup vs baseline: 1.1823x; 1.1823x over previous
//
#include <hip/hip_runtime.h>
#include <cstdint>
#include <cmath>

#define B_ 2
#define C_ 64
#define H_ 128
#define W_ 240
#define HW_ (H_*W_)
#define OFF_CH 144
#define MASK_CH 72
#define ALIGNED_SZ (B_*C_*HW_)   /* 3932160 floats */

typedef __bf16 bf16x8 __attribute__((ext_vector_type(8)));
typedef float f32x4 __attribute__((ext_vector_type(4)));
typedef short short4v __attribute__((ext_vector_type(4)));
typedef unsigned short ushort_t;

__device__ __forceinline__ ushort_t f2bf(float f) {
    unsigned u = __float_as_uint(f);
    u += 0x7fffu + ((u >> 16) & 1u);          // round-to-nearest-even
    return (ushort_t)(u >> 16);
}
__device__ __forceinline__ float bf2f(ushort_t b) {
    return __uint_as_float((unsigned)b << 16);
}
__device__ __forceinline__ float bf_lo(int q) {
    return __uint_as_float((unsigned)q << 16);
}
__device__ __forceinline__ float bf_hi(int q) {
    return __uint_as_float((unsigned)q & 0xffff0000u);
}

// workspace layout (byte offsets); total 32,956,416 B (< 33.4 MB proven OK)
#define W1P_OFF  0u
#define W2P_OFF  147456u
#define PIN_OFF  442368u      /* [B][2][HW][64] bf16 = 15,728,640 */
#define HBUF_OFF 16171008u    /* [B][H][W][64]  bf16 =  7,864,320 */
#define MASK_OFF 24035328u    /* [B][72][H][W]  bf16 =  8,847,360 */
#define WDP_OFF  32882688u    /* [18][4][64][8] bf16 =     73,728 */

// ---------------------------------------------------------------------------
// Repack all weights into MFMA A-fragment layouts (unchanged, proven).
// ---------------------------------------------------------------------------
__global__ __launch_bounds__(256) void pack_weights(
    const float* __restrict__ w1, const float* __restrict__ w2,
    const float* __restrict__ wd,
    ushort_t* __restrict__ w1pf, ushort_t* __restrict__ w2pf,
    ushort_t* __restrict__ wdp)
{
    int t = blockIdx.x * 256 + threadIdx.x;
    if (t < 73728) {
        int j = t & 7, lane = (t >> 3) & 63, r = t >> 9;
        int wv = r & 3, ct = r >> 2;
        int tap = ct % 9, chunk = ct / 9;
        int oc = wv * 16 + (lane & 15);
        int ci = chunk * 32 + ((lane >> 4) << 3) + j;
        w1pf[t] = f2bf(w1[((size_t)oc * 128 + ci) * 9 + tap]);
    } else if (t < 73728 + 147456) {
        int f = t - 73728;
        int j = f & 7, lane = (f >> 3) & 63, r = f >> 9;
        int wv = r & 3, q = r >> 2;
        int tap = q % 9, oc2 = q / 9;
        int chunk = oc2 & 1, ocg = oc2 >> 1;
        int oc = ocg * 64 + wv * 16 + (lane & 15);
        int ci = chunk * 32 + ((lane >> 4) << 3) + j;
        float v = (oc < 216) ? w2[((size_t)oc * 64 + ci) * 9 + tap] : 0.f;
        w2pf[f] = f2bf(v);
    } else if (t < 73728 + 147456 + 36864) {
        int f = t - 221184;
        int j = f & 7, lane = (f >> 3) & 63, sg = f >> 9;
        int g = sg & 3, s = sg >> 2;
        int oc = g * 16 + (lane & 15);
        int K = s * 32 + ((lane >> 4) << 3) + j;
        int dg = K / 72, rr = K - dg * 72;
        int tap = rr >> 3, ci = (dg << 3) + (rr & 7);
        wdp[f] = f2bf(wd[((size_t)oc * 64 + ci) * 9 + tap]);
    }
}

// ---------------------------------------------------------------------------
// Repack input into SPLIT layout (unchanged).
// ---------------------------------------------------------------------------
__global__ __launch_bounds__(256) void pack_input(
    const float* __restrict__ nbr, const float* __restrict__ ref,
    ushort_t* __restrict__ pin)
{
    int f = blockIdx.x * 256 + threadIdx.x;    // < 983040 = B*HW*16
    int civec = f & 15;
    int rem = f >> 4;                          // b*HW + pix
    int b = rem / HW_, pix = rem - b * HW_;
    const int half = civec >> 3;
    const float* src = (half == 0) ? (nbr + (size_t)b * 64 * HW_)
                                   : (ref + (size_t)b * 64 * HW_);
    int cbase = (civec & 7) * 8;
    union { ushort_t u[8]; int4 v; } o;
#pragma unroll
    for (int j = 0; j < 8; ++j)
        o.u[j] = f2bf(src[(size_t)(cbase + j) * HW_ + pix]);
    *(int4*)&pin[(((size_t)b * 2 + half) * HW_ + pix) * 64 + cbase] = o.v;
}

// ---------------------------------------------------------------------------
// conv1 via MFMA implicit GEMM (unchanged, proven).
// ---------------------------------------------------------------------------
__global__ __launch_bounds__(256) void conv1_mfma(
    const ushort_t* __restrict__ pin, const float* __restrict__ b1,
    const ushort_t* __restrict__ w1pf, ushort_t* __restrict__ hbuf)
{
    const int bx = blockIdx.x, y = blockIdx.y, b = blockIdx.z;
    const int x0 = bx * 48;
    const int tid = threadIdx.x;
    const int wv = tid >> 6, lane = tid & 63;
    const int l15 = lane & 15, k8 = (lane >> 4) << 3;

    __shared__ __align__(16) ushort_t s_in[3 * 50 * 40];

    f32x4 acc[3];
#pragma unroll
    for (int i = 0; i < 3; ++i) acc[i] = (f32x4){0.f, 0.f, 0.f, 0.f};

    for (int chunk = 0; chunk < 4; ++chunk) {
        const int ci0 = chunk << 5;
        for (int i = tid; i < 600; i += 256) {
            int cvec = i & 3, rc = i >> 2;
            int row = rc / 50, col = rc - row * 50;
            int gy = y + row - 1, gx = x0 + col - 1;
            int ci = ci0 + cvec * 8;
            int half = ci >> 6, cw = ci & 63;
            int4 v = {0, 0, 0, 0};
            if ((unsigned)gy < (unsigned)H_ && (unsigned)gx < (unsigned)W_)
                v = *(const int4*)&pin[(((size_t)b * 2 + half) * HW_ + (size_t)gy * W_ + gx) * 64 + cw];
            *(int4*)&s_in[(row * 50 + col) * 40 + cvec * 8] = v;
        }
        bf16x8 af[9];
#pragma unroll
        for (int tap = 0; tap < 9; ++tap)
            af[tap] = *(const bf16x8*)&w1pf[((((size_t)chunk * 9 + tap) * 4 + wv) * 64 + lane) * 8];
        __syncthreads();

#pragma unroll
        for (int tap = 0; tap < 9; ++tap) {
            const int ky = tap / 3, kx = tap - ky * 3;
#pragma unroll
            for (int pt = 0; pt < 3; ++pt) {
                int col = (pt << 4) + l15 + kx;
                bf16x8 bb = *(const bf16x8*)&s_in[(ky * 50 + col) * 40 + k8];
                acc[pt] = __builtin_amdgcn_mfma_f32_16x16x32_bf16(af[tap], bb, acc[pt], 0, 0, 0);
            }
        }
        __syncthreads();
    }

    const int ocb = (wv << 4) + ((lane >> 4) << 2);
    float bias[4];
#pragma unroll
    for (int r = 0; r < 4; ++r) bias[r] = b1[ocb + r];
#pragma unroll
    for (int pt = 0; pt < 3; ++pt) {
        int gx = x0 + (pt << 4) + l15;
        union { ushort_t u[4]; short4v s; } o;
#pragma unroll
        for (int r = 0; r < 4; ++r) {
            float v = acc[pt][r] + bias[r];
            v = (v >= 0.f) ? v : 0.1f * v;
            o.u[r] = f2bf(v);
        }
        *(short4v*)&hbuf[(((size_t)b * H_ + y) * W_ + gx) * 64 + ocb] = o.s;
    }
}

// ---------------------------------------------------------------------------
// conv2 via MFMA implicit GEMM (unchanged, proven).
// ---------------------------------------------------------------------------
__global__ __launch_bounds__(256) void conv2_mfma(
    const ushort_t* __restrict__ hbuf, const float* __restrict__ b2,
    const ushort_t* __restrict__ w2pf,
    float* __restrict__ off_out, ushort_t* __restrict__ maskbuf)
{
    const int bx = blockIdx.x, y = blockIdx.y;
    const int b = blockIdx.z >> 2, ocg = blockIdx.z & 3;
    const int x0 = bx * 48;
    const int tid = threadIdx.x;
    const int wv = tid >> 6, lane = tid & 63;
    const int l15 = lane & 15, k8 = (lane >> 4) << 3;

    __shared__ __align__(16) ushort_t s_in[3 * 50 * 40];

    f32x4 acc[3];
#pragma unroll
    for (int i = 0; i < 3; ++i) acc[i] = (f32x4){0.f, 0.f, 0.f, 0.f};

    for (int chunk = 0; chunk < 2; ++chunk) {
        const int ci0 = chunk << 5;
        for (int i = tid; i < 600; i += 256) {
            int cvec = i & 3, rc = i >> 2;
            int row = rc / 50, col = rc - row * 50;
            int gy = y + row - 1, gx = x0 + col - 1;
            int4 v = {0, 0, 0, 0};
            if ((unsigned)gy < (unsigned)H_ && (unsigned)gx < (unsigned)W_)
                v = *(const int4*)&hbuf[(((size_t)b * H_ + gy) * W_ + gx) * 64 + ci0 + cvec * 8];
            *(int4*)&s_in[(row * 50 + col) * 40 + cvec * 8] = v;
        }
        bf16x8 af[9];
#pragma unroll
        for (int tap = 0; tap < 9; ++tap)
            af[tap] = *(const bf16x8*)&w2pf[(((((size_t)ocg * 2 + chunk) * 9 + tap) * 4 + wv) * 64 + lane) * 8];
        __syncthreads();

#pragma unroll
        for (int tap = 0; tap < 9; ++tap) {
            const int ky = tap / 3, kx = tap - ky * 3;
#pragma unroll
            for (int pt = 0; pt < 3; ++pt) {
                int col = (pt << 4) + l15 + kx;
                bf16x8 bb = *(const bf16x8*)&s_in[(ky * 50 + col) * 40 + k8];
                acc[pt] = __builtin_amdgcn_mfma_f32_16x16x32_bf16(af[tap], bb, acc[pt], 0, 0, 0);
            }
        }
        __syncthreads();
    }

    const int ocb = (wv << 4) + ((lane >> 4) << 2);
#pragma unroll
    for (int pt = 0; pt < 3; ++pt) {
        int gx = x0 + (pt << 4) + l15;
#pragma unroll
        for (int r = 0; r < 4; ++r) {
            int co = (ocg << 6) + ocb + r;
            if (co < 216) {
                float v = acc[pt][r] + b2[co];
                if (co < 144) {
                    off_out[((size_t)b * OFF_CH + co) * HW_ + y * W_ + gx] = v;
                } else {
                    maskbuf[((size_t)b * MASK_CH + (co - 144)) * HW_ + y * W_ + gx] =
                        f2bf(1.f / (1.f + expf(-v)));
                }
            }
        }
    }
}

// ---------------------------------------------------------------------------
// dconv v7: barrier-free, 2-deep gather pipeline with STATIC ping-pong
// stages (spill-proof: by-value structs, unroll-2 static indexing,
// branch-free clamped tail).  Wave = 16 px x 64 oc x full K.
// ---------------------------------------------------------------------------
struct OffRec { float dy, dx, m; };
struct Stage  { int4 g0, g1, g2, g3; float w0, w1, w2, w3; };

__global__ __launch_bounds__(256, 4) void dconv_mfma(
    const ushort_t* __restrict__ pin,
    const float* __restrict__ offs,
    const ushort_t* __restrict__ maskbuf,
    const ushort_t* __restrict__ wdp, const float* __restrict__ bd,
    float* __restrict__ outp)
{
    const int bid = blockIdx.x;
    const int nid = (bid & 7) * 120 + (bid >> 3);
    const int b   = nid / 480;
    const int rr_ = nid - b * 480;
    const int byt = rr_ / 15, bxt = rr_ - byt * 15;   // byt 0..31
    const int x0 = bxt << 4, y0 = byt << 2;

    const int tid = threadIdx.x;
    const int wv = tid >> 6, lane = tid & 63;
    const int l15 = lane & 15, hi4 = lane >> 4;       // hi4 = k-group

    const int x = x0 + l15, y = y0 + wv;              // this lane's pixel
    const size_t pix = (size_t)y * W_ + x;
    const size_t pinb = (size_t)(b * 2) * HW_;        // nbr half base
    const float* offp = offs + (size_t)b * OFF_CH * HW_ + pix;
    const ushort_t* mkp = maskbuf + (size_t)b * MASK_CH * HW_ + pix;

    f32x4 acc0 = {0.f,0.f,0.f,0.f}, acc1 = {0.f,0.f,0.f,0.f};
    f32x4 acc2 = {0.f,0.f,0.f,0.f}, acc3 = {0.f,0.f,0.f,0.f};

    auto load_off = [&](int s) -> OffRec {
        int K = (s << 5) + (hi4 << 3);
        int dg = K / 72, r2 = K - dg * 72, tap = r2 >> 3;
        OffRec o;
        o.dy = offp[(size_t)(dg * 18 + tap) * HW_];
        o.dx = offp[(size_t)(dg * 18 + 9 + tap) * HW_];
        o.m  = bf2f(mkp[(size_t)(dg * 9 + tap) * HW_]);
        return o;
    };
    auto sample = [&](int s, OffRec of) -> Stage {
        int K = (s << 5) + (hi4 << 3);
        int dg = K / 72, rm = K - dg * 72, tap = rm >> 3;
        int ky = tap / 3 - 1, kx = tap % 3 - 1;
        float py  = (float)(y + ky) + of.dy;
        float pxf = (float)(x + kx) + of.dx;
        float yf = floorf(py), xf = floorf(pxf);
        float wy = py - yf, wx = pxf - xf;
        int yi = (int)yf, xi = (int)xf;
        bool y0v = (unsigned)yi < (unsigned)H_;
        bool y1v = (unsigned)(yi + 1) < (unsigned)H_;
        bool x0v = (unsigned)xi < (unsigned)W_;
        bool x1v = (unsigned)(xi + 1) < (unsigned)W_;
        Stage st;
        st.w0 = (y0v && x0v) ? (1.f - wy) * (1.f - wx) * of.m : 0.f;
        st.w1 = (y0v && x1v) ? (1.f - wy) * wx         * of.m : 0.f;
        st.w2 = (y1v && x0v) ? wy         * (1.f - wx) * of.m : 0.f;
        st.w3 = (y1v && x1v) ? wy         * wx         * of.m : 0.f;
        int yc0 = min(max(yi, 0), H_ - 1), yc1 = min(max(yi + 1, 0), H_ - 1);
        int xc0 = min(max(xi, 0), W_ - 1), xc1 = min(max(xi + 1, 0), W_ - 1);
        const int cofs = dg << 3;
        st.g0 = *(const int4*)&pin[(pinb + yc0 * W_ + xc0) * 64 + cofs];
        st.g1 = *(const int4*)&pin[(pinb + yc0 * W_ + xc1) * 64 + cofs];
        st.g2 = *(const int4*)&pin[(pinb + yc1 * W_ + xc0) * 64 + cofs];
        st.g3 = *(const int4*)&pin[(pinb + yc1 * W_ + xc1) * 64 + cofs];
        return st;
    };

    // ---- prologue: stages for slices 0,1 in flight; offsets for 2,3 ----
    Stage  P0 = sample(0, load_off(0));
    Stage  P1 = sample(1, load_off(1));
    OffRec O0 = load_off(2);
    OffRec O1 = load_off(3);

#pragma unroll 2
    for (int s = 0; s < 18; ++s) {
        // A-fragments for slice s (L1/L2-resident)
        const ushort_t* wp = wdp + (((size_t)(s << 2) * 64) + lane) * 8;
        bf16x8 a0 = *(const bf16x8*)(wp);
        bf16x8 a1 = *(const bf16x8*)(wp + 512);
        bf16x8 a2 = *(const bf16x8*)(wp + 1024);
        bf16x8 a3 = *(const bf16x8*)(wp + 1536);

        // consume stage (s&1): blend -> bfrag (frees the stage registers)
        Stage cur = (s & 1) ? P1 : P0;
        bf16x8 bfrag;
        {
            const int* c00 = (const int*)&cur.g0; const int* c01 = (const int*)&cur.g1;
            const int* c10 = (const int*)&cur.g2; const int* c11 = (const int*)&cur.g3;
#pragma unroll
            for (int j = 0; j < 4; ++j) {
                float lo = cur.w0 * bf_lo(c00[j]) + cur.w1 * bf_lo(c01[j])
                         + cur.w2 * bf_lo(c10[j]) + cur.w3 * bf_lo(c11[j]);
                float hv = cur.w0 * bf_hi(c00[j]) + cur.w1 * bf_hi(c01[j])
                         + cur.w2 * bf_hi(c10[j]) + cur.w3 * bf_hi(c11[j]);
                bfrag[2 * j]     = (__bf16)lo;
                bfrag[2 * j + 1] = (__bf16)hv;
            }
        }

        // re-fill the consumed stage with slice s+2 (clamped tail: duplicate
        // gathers of slice 17, never consumed — issue/consume pairing exact)
        int s2 = min(s + 2, 17);
        if (s & 1) P1 = sample(s2, O1); else P0 = sample(s2, O0);
        // refresh offset reg for slice s+4
        int s4 = min(s + 4, 17);
        if (s & 1) O1 = load_off(s4); else O0 = load_off(s4);

        acc0 = __builtin_amdgcn_mfma_f32_16x16x32_bf16(a0, bfrag, acc0, 0, 0, 0);
        acc1 = __builtin_amdgcn_mfma_f32_16x16x32_bf16(a1, bfrag, acc1, 0, 0, 0);
        acc2 = __builtin_amdgcn_mfma_f32_16x16x32_bf16(a2, bfrag, acc2, 0, 0, 0);
        acc3 = __builtin_amdgcn_mfma_f32_16x16x32_bf16(a3, bfrag, acc3, 0, 0, 0);
    }

    // epilogue: acc_g[r] -> oc = g*16 + hi4*4 + r at pixel (y, x0+l15)
    const int ocr = hi4 << 2;
    const size_t pbase = (size_t)b * C_ * HW_ + (size_t)y * W_ + x0 + l15;
#pragma unroll
    for (int r = 0; r < 4; ++r) {
        int oc0 = ocr + r;
        outp[pbase + (size_t)(oc0)      * HW_] = acc0[r] + bd[oc0];
        outp[pbase + (size_t)(oc0 + 16) * HW_] = acc1[r] + bd[oc0 + 16];
        outp[pbase + (size_t)(oc0 + 32) * HW_] = acc2[r] + bd[oc0 + 32];
        outp[pbase + (size_t)(oc0 + 48) * HW_] = acc3[r] + bd[oc0 + 48];
    }
}

// ---------------------------------------------------------------------------
extern "C" void kernel_launch(void* const* d_in, const int* in_sizes, int n_in,
                              void* d_out, int out_size, void* d_ws, size_t ws_size,
                              hipStream_t stream)
{
    const float* nbr = (const float*)d_in[0];
    const float* ref = (const float*)d_in[1];
    const float* w1  = (const float*)d_in[2];
    const float* b1  = (const float*)d_in[3];
    const float* w2  = (const float*)d_in[4];
    const float* b2  = (const float*)d_in[5];
    const float* wd  = (const float*)d_in[6];
    const float* bd  = (const float*)d_in[7];

    float* out     = (float*)d_out;
    float* off_out = out + ALIGNED_SZ;

    char* ws = (char*)d_ws;
    ushort_t* w1pf  = (ushort_t*)(ws + W1P_OFF);
    ushort_t* w2pf  = (ushort_t*)(ws + W2P_OFF);
    ushort_t* pin   = (ushort_t*)(ws + PIN_OFF);
    ushort_t* hbufp = (ushort_t*)(ws + HBUF_OFF);
    ushort_t* maskp = (ushort_t*)(ws + MASK_OFF);
    ushort_t* wdp   = (ushort_t*)(ws + WDP_OFF);

    dim3 blk(256, 1, 1);
    pack_weights<<<1008, blk, 0, stream>>>(w1, w2, wd, w1pf, w2pf, wdp);
    pack_input<<<3840, blk, 0, stream>>>(nbr, ref, pin);
    conv1_mfma<<<dim3(5, 128, 2), blk, 0, stream>>>(pin, b1, w1pf, hbufp);
    conv2_mfma<<<dim3(5, 128, 8), blk, 0, stream>>>(hbufp, b2, w2pf, off_out, maskp);
    dconv_mfma<<<960, blk, 0, stream>>>(pin, off_out, maskp, wdp, bd, out);
}

// Round 11
// 138.329 us; speedup vs baseline: 1.3640x; 1.1537x over previous
//
#include <hip/hip_runtime.h>
#include <cstdint>
#include <cmath>

#define B_ 2
#define C_ 64
#define H_ 128
#define W_ 240
#define HW_ (H_*W_)
#define OFF_CH 144
#define MASK_CH 72
#define ALIGNED_SZ (B_*C_*HW_)   /* 3932160 floats */

typedef __bf16 bf16x8 __attribute__((ext_vector_type(8)));
typedef float f32x4 __attribute__((ext_vector_type(4)));
typedef short short4v __attribute__((ext_vector_type(4)));
typedef unsigned short ushort_t;

__device__ __forceinline__ ushort_t f2bf(float f) {
    unsigned u = __float_as_uint(f);
    u += 0x7fffu + ((u >> 16) & 1u);          // round-to-nearest-even
    return (ushort_t)(u >> 16);
}
__device__ __forceinline__ float bf2f(ushort_t b) {
    return __uint_as_float((unsigned)b << 16);
}
__device__ __forceinline__ float bf_lo(int q) {
    return __uint_as_float((unsigned)q << 16);
}
__device__ __forceinline__ float bf_hi(int q) {
    return __uint_as_float((unsigned)q & 0xffff0000u);
}

// workspace layout (byte offsets); total 32,956,416 B (< 33.4 MB proven OK)
// pin v2: nbr half = 8 per-dg planes [dg][HW][8ch] (16B px records);
//         ref half = [HW][64] (unchanged).
#define W1P_OFF  0u
#define W2P_OFF  147456u
#define PIN_OFF  442368u      /* [B][2][HW][64] bf16 = 15,728,640 */
#define HBUF_OFF 16171008u    /* [B][H][W][64]  bf16 =  7,864,320 */
#define MASK_OFF 24035328u    /* [B][72][H][W]  bf16 =  8,847,360 */
#define WDP_OFF  32882688u    /* [18][4][64][8] bf16 =     73,728 */

// ---------------------------------------------------------------------------
// Repack all weights into MFMA A-fragment layouts (unchanged, proven).
// ---------------------------------------------------------------------------
__global__ __launch_bounds__(256) void pack_weights(
    const float* __restrict__ w1, const float* __restrict__ w2,
    const float* __restrict__ wd,
    ushort_t* __restrict__ w1pf, ushort_t* __restrict__ w2pf,
    ushort_t* __restrict__ wdp)
{
    int t = blockIdx.x * 256 + threadIdx.x;
    if (t < 73728) {
        int j = t & 7, lane = (t >> 3) & 63, r = t >> 9;
        int wv = r & 3, ct = r >> 2;
        int tap = ct % 9, chunk = ct / 9;
        int oc = wv * 16 + (lane & 15);
        int ci = chunk * 32 + ((lane >> 4) << 3) + j;
        w1pf[t] = f2bf(w1[((size_t)oc * 128 + ci) * 9 + tap]);
    } else if (t < 73728 + 147456) {
        int f = t - 73728;
        int j = f & 7, lane = (f >> 3) & 63, r = f >> 9;
        int wv = r & 3, q = r >> 2;
        int tap = q % 9, oc2 = q / 9;
        int chunk = oc2 & 1, ocg = oc2 >> 1;
        int oc = ocg * 64 + wv * 16 + (lane & 15);
        int ci = chunk * 32 + ((lane >> 4) << 3) + j;
        float v = (oc < 216) ? w2[((size_t)oc * 64 + ci) * 9 + tap] : 0.f;
        w2pf[f] = f2bf(v);
    } else if (t < 73728 + 147456 + 36864) {
        int f = t - 221184;
        int j = f & 7, lane = (f >> 3) & 63, sg = f >> 9;
        int g = sg & 3, s = sg >> 2;
        int oc = g * 16 + (lane & 15);
        int K = s * 32 + ((lane >> 4) << 3) + j;
        int dg = K / 72, rr = K - dg * 72;
        int tap = rr >> 3, ci = (dg << 3) + (rr & 7);
        wdp[f] = f2bf(wd[((size_t)oc * 64 + ci) * 9 + tap]);
    }
}

// ---------------------------------------------------------------------------
// Repack input. nbr -> per-dg planes [b][dg][HW][8]; ref -> [b][HW][64].
// ---------------------------------------------------------------------------
__global__ __launch_bounds__(256) void pack_input(
    const float* __restrict__ nbr, const float* __restrict__ ref,
    ushort_t* __restrict__ pin)
{
    int f = blockIdx.x * 256 + threadIdx.x;    // < 983040 = B*HW*16
    int civec = f & 15;
    int rem = f >> 4;                          // b*HW + pix
    int b = rem / HW_, pix = rem - b * HW_;
    const int half = civec >> 3;
    const float* src = (half == 0) ? (nbr + (size_t)b * 64 * HW_)
                                   : (ref + (size_t)b * 64 * HW_);
    int cbase = (civec & 7) * 8;
    union { ushort_t u[8]; int4 v; } o;
#pragma unroll
    for (int j = 0; j < 8; ++j)
        o.u[j] = f2bf(src[(size_t)(cbase + j) * HW_ + pix]);
    size_t dst;
    if (half == 0) {    // dg-plane layout: dg = cbase>>3
        dst = (size_t)b * 2 * HW_ * 64 + (size_t)(civec & 7) * HW_ * 8 + (size_t)pix * 8;
    } else {            // ref half: [HW][64]
        dst = ((size_t)(b * 2 + 1) * HW_ + pix) * 64 + cbase;
    }
    *(int4*)&pin[dst] = o.v;
}

// ---------------------------------------------------------------------------
// conv1 via MFMA implicit GEMM (address math adapted to pin v2).
// ---------------------------------------------------------------------------
__global__ __launch_bounds__(256) void conv1_mfma(
    const ushort_t* __restrict__ pin, const float* __restrict__ b1,
    const ushort_t* __restrict__ w1pf, ushort_t* __restrict__ hbuf)
{
    const int bx = blockIdx.x, y = blockIdx.y, b = blockIdx.z;
    const int x0 = bx * 48;
    const int tid = threadIdx.x;
    const int wv = tid >> 6, lane = tid & 63;
    const int l15 = lane & 15, k8 = (lane >> 4) << 3;

    __shared__ __align__(16) ushort_t s_in[3 * 50 * 40];

    f32x4 acc[3];
#pragma unroll
    for (int i = 0; i < 3; ++i) acc[i] = (f32x4){0.f, 0.f, 0.f, 0.f};

    for (int chunk = 0; chunk < 4; ++chunk) {
        const int ci0 = chunk << 5;
        for (int i = tid; i < 600; i += 256) {
            int cvec = i & 3, rc = i >> 2;
            int row = rc / 50, col = rc - row * 50;
            int gy = y + row - 1, gx = x0 + col - 1;
            int ci = ci0 + cvec * 8;
            int half = ci >> 6, cw = ci & 63;
            int4 v = {0, 0, 0, 0};
            if ((unsigned)gy < (unsigned)H_ && (unsigned)gx < (unsigned)W_) {
                size_t srca;
                if (half == 0)
                    srca = (size_t)b * 2 * HW_ * 64 + (size_t)(cw >> 3) * HW_ * 8
                         + (size_t)(gy * W_ + gx) * 8;
                else
                    srca = ((size_t)(b * 2 + 1) * HW_ + (size_t)gy * W_ + gx) * 64 + cw;
                v = *(const int4*)&pin[srca];
            }
            *(int4*)&s_in[(row * 50 + col) * 40 + cvec * 8] = v;
        }
        bf16x8 af[9];
#pragma unroll
        for (int tap = 0; tap < 9; ++tap)
            af[tap] = *(const bf16x8*)&w1pf[((((size_t)chunk * 9 + tap) * 4 + wv) * 64 + lane) * 8];
        __syncthreads();

#pragma unroll
        for (int tap = 0; tap < 9; ++tap) {
            const int ky = tap / 3, kx = tap - ky * 3;
#pragma unroll
            for (int pt = 0; pt < 3; ++pt) {
                int col = (pt << 4) + l15 + kx;
                bf16x8 bb = *(const bf16x8*)&s_in[(ky * 50 + col) * 40 + k8];
                acc[pt] = __builtin_amdgcn_mfma_f32_16x16x32_bf16(af[tap], bb, acc[pt], 0, 0, 0);
            }
        }
        __syncthreads();
    }

    const int ocb = (wv << 4) + ((lane >> 4) << 2);
    float bias[4];
#pragma unroll
    for (int r = 0; r < 4; ++r) bias[r] = b1[ocb + r];
#pragma unroll
    for (int pt = 0; pt < 3; ++pt) {
        int gx = x0 + (pt << 4) + l15;
        union { ushort_t u[4]; short4v s; } o;
#pragma unroll
        for (int r = 0; r < 4; ++r) {
            float v = acc[pt][r] + bias[r];
            v = (v >= 0.f) ? v : 0.1f * v;
            o.u[r] = f2bf(v);
        }
        *(short4v*)&hbuf[(((size_t)b * H_ + y) * W_ + gx) * 64 + ocb] = o.s;
    }
}

// ---------------------------------------------------------------------------
// conv2 via MFMA implicit GEMM (unchanged, proven).
// ---------------------------------------------------------------------------
__global__ __launch_bounds__(256) void conv2_mfma(
    const ushort_t* __restrict__ hbuf, const float* __restrict__ b2,
    const ushort_t* __restrict__ w2pf,
    float* __restrict__ off_out, ushort_t* __restrict__ maskbuf)
{
    const int bx = blockIdx.x, y = blockIdx.y;
    const int b = blockIdx.z >> 2, ocg = blockIdx.z & 3;
    const int x0 = bx * 48;
    const int tid = threadIdx.x;
    const int wv = tid >> 6, lane = tid & 63;
    const int l15 = lane & 15, k8 = (lane >> 4) << 3;

    __shared__ __align__(16) ushort_t s_in[3 * 50 * 40];

    f32x4 acc[3];
#pragma unroll
    for (int i = 0; i < 3; ++i) acc[i] = (f32x4){0.f, 0.f, 0.f, 0.f};

    for (int chunk = 0; chunk < 2; ++chunk) {
        const int ci0 = chunk << 5;
        for (int i = tid; i < 600; i += 256) {
            int cvec = i & 3, rc = i >> 2;
            int row = rc / 50, col = rc - row * 50;
            int gy = y + row - 1, gx = x0 + col - 1;
            int4 v = {0, 0, 0, 0};
            if ((unsigned)gy < (unsigned)H_ && (unsigned)gx < (unsigned)W_)
                v = *(const int4*)&hbuf[(((size_t)b * H_ + gy) * W_ + gx) * 64 + ci0 + cvec * 8];
            *(int4*)&s_in[(row * 50 + col) * 40 + cvec * 8] = v;
        }
        bf16x8 af[9];
#pragma unroll
        for (int tap = 0; tap < 9; ++tap)
            af[tap] = *(const bf16x8*)&w2pf[(((((size_t)ocg * 2 + chunk) * 9 + tap) * 4 + wv) * 64 + lane) * 8];
        __syncthreads();

#pragma unroll
        for (int tap = 0; tap < 9; ++tap) {
            const int ky = tap / 3, kx = tap - ky * 3;
#pragma unroll
            for (int pt = 0; pt < 3; ++pt) {
                int col = (pt << 4) + l15 + kx;
                bf16x8 bb = *(const bf16x8*)&s_in[(ky * 50 + col) * 40 + k8];
                acc[pt] = __builtin_amdgcn_mfma_f32_16x16x32_bf16(af[tap], bb, acc[pt], 0, 0, 0);
            }
        }
        __syncthreads();
    }

    const int ocb = (wv << 4) + ((lane >> 4) << 2);
#pragma unroll
    for (int pt = 0; pt < 3; ++pt) {
        int gx = x0 + (pt << 4) + l15;
#pragma unroll
        for (int r = 0; r < 4; ++r) {
            int co = (ocg << 6) + ocb + r;
            if (co < 216) {
                float v = acc[pt][r] + b2[co];
                if (co < 144) {
                    off_out[((size_t)b * OFF_CH + co) * HW_ + y * W_ + gx] = v;
                } else {
                    maskbuf[((size_t)b * MASK_CH + (co - 144)) * HW_ + y * W_ + gx] =
                        f2bf(1.f / (1.f + expf(-v)));
                }
            }
        }
    }
}

// ---------------------------------------------------------------------------
// dconv v8: v7 barrier-free ping-pong structure + per-dg-plane gathers.
// Gather records are now 16B/px (dg plane) -> 16 consecutive-px lanes read
// 256B contiguous (4 lines) instead of 16 scattered lines: ~4x fewer L1
// transactions, no over-read.
// ---------------------------------------------------------------------------
struct OffRec { float dy, dx, m; };
struct Stage  { int4 g0, g1, g2, g3; float w0, w1, w2, w3; };

__global__ __launch_bounds__(256, 4) void dconv_mfma(
    const ushort_t* __restrict__ pin,
    const float* __restrict__ offs,
    const ushort_t* __restrict__ maskbuf,
    const ushort_t* __restrict__ wdp, const float* __restrict__ bd,
    float* __restrict__ outp)
{
    const int bid = blockIdx.x;
    const int nid = (bid & 7) * 120 + (bid >> 3);
    const int b   = nid / 480;
    const int rr_ = nid - b * 480;
    const int byt = rr_ / 15, bxt = rr_ - byt * 15;   // byt 0..31
    const int x0 = bxt << 4, y0 = byt << 2;

    const int tid = threadIdx.x;
    const int wv = tid >> 6, lane = tid & 63;
    const int l15 = lane & 15, hi4 = lane >> 4;       // hi4 = k-group

    const int x = x0 + l15, y = y0 + wv;              // this lane's pixel
    const size_t pix = (size_t)y * W_ + x;
    const size_t pinb = (size_t)b * 2 * HW_ * 64;     // nbr dg-planes base
    const float* offp = offs + (size_t)b * OFF_CH * HW_ + pix;
    const ushort_t* mkp = maskbuf + (size_t)b * MASK_CH * HW_ + pix;

    f32x4 acc0 = {0.f,0.f,0.f,0.f}, acc1 = {0.f,0.f,0.f,0.f};
    f32x4 acc2 = {0.f,0.f,0.f,0.f}, acc3 = {0.f,0.f,0.f,0.f};

    auto load_off = [&](int s) -> OffRec {
        int K = (s << 5) + (hi4 << 3);
        int dg = K / 72, r2 = K - dg * 72, tap = r2 >> 3;
        OffRec o;
        o.dy = offp[(size_t)(dg * 18 + tap) * HW_];
        o.dx = offp[(size_t)(dg * 18 + 9 + tap) * HW_];
        o.m  = bf2f(mkp[(size_t)(dg * 9 + tap) * HW_]);
        return o;
    };
    auto sample = [&](int s, OffRec of) -> Stage {
        int K = (s << 5) + (hi4 << 3);
        int dg = K / 72, rm = K - dg * 72, tap = rm >> 3;
        int ky = tap / 3 - 1, kx = tap % 3 - 1;
        float py  = (float)(y + ky) + of.dy;
        float pxf = (float)(x + kx) + of.dx;
        float yf = floorf(py), xf = floorf(pxf);
        float wy = py - yf, wx = pxf - xf;
        int yi = (int)yf, xi = (int)xf;
        bool y0v = (unsigned)yi < (unsigned)H_;
        bool y1v = (unsigned)(yi + 1) < (unsigned)H_;
        bool x0v = (unsigned)xi < (unsigned)W_;
        bool x1v = (unsigned)(xi + 1) < (unsigned)W_;
        Stage st;
        st.w0 = (y0v && x0v) ? (1.f - wy) * (1.f - wx) * of.m : 0.f;
        st.w1 = (y0v && x1v) ? (1.f - wy) * wx         * of.m : 0.f;
        st.w2 = (y1v && x0v) ? wy         * (1.f - wx) * of.m : 0.f;
        st.w3 = (y1v && x1v) ? wy         * wx         * of.m : 0.f;
        int yc0 = min(max(yi, 0), H_ - 1), yc1 = min(max(yi + 1, 0), H_ - 1);
        int xc0 = min(max(xi, 0), W_ - 1), xc1 = min(max(xi + 1, 0), W_ - 1);
        const size_t dgb = pinb + (size_t)dg * HW_ * 8;   // 16B px records
        st.g0 = *(const int4*)&pin[dgb + (size_t)(yc0 * W_ + xc0) * 8];
        st.g1 = *(const int4*)&pin[dgb + (size_t)(yc0 * W_ + xc1) * 8];
        st.g2 = *(const int4*)&pin[dgb + (size_t)(yc1 * W_ + xc0) * 8];
        st.g3 = *(const int4*)&pin[dgb + (size_t)(yc1 * W_ + xc1) * 8];
        return st;
    };

    // ---- prologue: stages for slices 0,1 in flight; offsets for 2,3 ----
    Stage  P0 = sample(0, load_off(0));
    Stage  P1 = sample(1, load_off(1));
    OffRec O0 = load_off(2);
    OffRec O1 = load_off(3);

#pragma unroll 2
    for (int s = 0; s < 18; ++s) {
        // A-fragments for slice s (L1/L2-resident)
        const ushort_t* wp = wdp + (((size_t)(s << 2) * 64) + lane) * 8;
        bf16x8 a0 = *(const bf16x8*)(wp);
        bf16x8 a1 = *(const bf16x8*)(wp + 512);
        bf16x8 a2 = *(const bf16x8*)(wp + 1024);
        bf16x8 a3 = *(const bf16x8*)(wp + 1536);

        // consume stage (s&1): blend -> bfrag  (s&1 is static after unroll)
        Stage cur = (s & 1) ? P1 : P0;
        bf16x8 bfrag;
        {
            const int* c00 = (const int*)&cur.g0; const int* c01 = (const int*)&cur.g1;
            const int* c10 = (const int*)&cur.g2; const int* c11 = (const int*)&cur.g3;
#pragma unroll
            for (int j = 0; j < 4; ++j) {
                float lo = cur.w0 * bf_lo(c00[j]) + cur.w1 * bf_lo(c01[j])
                         + cur.w2 * bf_lo(c10[j]) + cur.w3 * bf_lo(c11[j]);
                float hv = cur.w0 * bf_hi(c00[j]) + cur.w1 * bf_hi(c01[j])
                         + cur.w2 * bf_hi(c10[j]) + cur.w3 * bf_hi(c11[j]);
                bfrag[2 * j]     = (__bf16)lo;
                bfrag[2 * j + 1] = (__bf16)hv;
            }
        }

        // re-fill consumed stage with slice s+2 (clamped tail)
        int s2 = min(s + 2, 17);
        if (s & 1) P1 = sample(s2, O1); else P0 = sample(s2, O0);
        int s4 = min(s + 4, 17);
        if (s & 1) O1 = load_off(s4); else O0 = load_off(s4);

        acc0 = __builtin_amdgcn_mfma_f32_16x16x32_bf16(a0, bfrag, acc0, 0, 0, 0);
        acc1 = __builtin_amdgcn_mfma_f32_16x16x32_bf16(a1, bfrag, acc1, 0, 0, 0);
        acc2 = __builtin_amdgcn_mfma_f32_16x16x32_bf16(a2, bfrag, acc2, 0, 0, 0);
        acc3 = __builtin_amdgcn_mfma_f32_16x16x32_bf16(a3, bfrag, acc3, 0, 0, 0);
    }

    // epilogue: acc_g[r] -> oc = g*16 + hi4*4 + r at pixel (y, x0+l15)
    const int ocr = hi4 << 2;
    const size_t pbase = (size_t)b * C_ * HW_ + (size_t)y * W_ + x0 + l15;
#pragma unroll
    for (int r = 0; r < 4; ++r) {
        int oc0 = ocr + r;
        outp[pbase + (size_t)(oc0)      * HW_] = acc0[r] + bd[oc0];
        outp[pbase + (size_t)(oc0 + 16) * HW_] = acc1[r] + bd[oc0 + 16];
        outp[pbase + (size_t)(oc0 + 32) * HW_] = acc2[r] + bd[oc0 + 32];
        outp[pbase + (size_t)(oc0 + 48) * HW_] = acc3[r] + bd[oc0 + 48];
    }
}

// ---------------------------------------------------------------------------
extern "C" void kernel_launch(void* const* d_in, const int* in_sizes, int n_in,
                              void* d_out, int out_size, void* d_ws, size_t ws_size,
                              hipStream_t stream)
{
    const float* nbr = (const float*)d_in[0];
    const float* ref = (const float*)d_in[1];
    const float* w1  = (const float*)d_in[2];
    const float* b1  = (const float*)d_in[3];
    const float* w2  = (const float*)d_in[4];
    const float* b2  = (const float*)d_in[5];
    const float* wd  = (const float*)d_in[6];
    const float* bd  = (const float*)d_in[7];

    float* out     = (float*)d_out;
    float* off_out = out + ALIGNED_SZ;

    char* ws = (char*)d_ws;
    ushort_t* w1pf  = (ushort_t*)(ws + W1P_OFF);
    ushort_t* w2pf  = (ushort_t*)(ws + W2P_OFF);
    ushort_t* pin   = (ushort_t*)(ws + PIN_OFF);
    ushort_t* hbufp = (ushort_t*)(ws + HBUF_OFF);
    ushort_t* maskp = (ushort_t*)(ws + MASK_OFF);
    ushort_t* wdp   = (ushort_t*)(ws + WDP_OFF);

    dim3 blk(256, 1, 1);
    pack_weights<<<1008, blk, 0, stream>>>(w1, w2, wd, w1pf, w2pf, wdp);
    pack_input<<<3840, blk, 0, stream>>>(nbr, ref, pin);
    conv1_mfma<<<dim3(5, 128, 2), blk, 0, stream>>>(pin, b1, w1pf, hbufp);
    conv2_mfma<<<dim3(5, 128, 8), blk, 0, stream>>>(hbufp, b2, w2pf, off_out, maskp);
    dconv_mfma<<<960, blk, 0, stream>>>(pin, off_out, maskp, wdp, bd, out);
}